// Round 10
// baseline (173.007 us; speedup 1.0000x reference)
//
#include <hip/hip_runtime.h>

typedef __attribute__((ext_vector_type(8))) short s16x8;
typedef __attribute__((ext_vector_type(8))) ushort u16x8;
typedef __attribute__((ext_vector_type(4))) ushort u16x4;
typedef __attribute__((ext_vector_type(4))) float f32x4v;

namespace {

constexpr int kB = 2;
constexpr int kN = 16384;
constexpr int kC = 256;
constexpr int kQR = 1024;  // q rows per batch that reach the output

__device__ __forceinline__ ushort f2bf(float f) {
  union { float f; uint u; } v; v.f = f;
  uint u = v.u + 0x7fffu + ((v.u >> 16) & 1u);
  return (ushort)(u >> 16);
}

__device__ __forceinline__ float phi_act(float x) {
  // elu(elu(x)+1)+1 == x>0 ? x+2 : exp(x)+1
  return x > 0.f ? x + 2.f : __expf(x) + 1.f;
}

// ---- 1. weight transpose+convert: W[k][j] f32 -> WT[j][k] bf16
__global__ __launch_bounds__(256) void wt_kernel(const float* __restrict__ Wq,
                                                 const float* __restrict__ Wk,
                                                 ushort* __restrict__ WqT,
                                                 ushort* __restrict__ WkT) {
  __shared__ float ts[64][65];
  const float* W = blockIdx.z ? Wk : Wq;
  ushort* WT = blockIdx.z ? WkT : WqT;
  const int bi = blockIdx.x, bj = blockIdx.y, t = threadIdx.x;
  for (int rep = 0; rep < 16; ++rep) {
    int e = rep * 256 + t, r = e >> 6, c = e & 63;
    ts[r][c] = W[(size_t)(bi * 64 + r) * kC + bj * 64 + c];
  }
  __syncthreads();
  for (int rep = 0; rep < 16; ++rep) {
    int e = rep * 256 + t, j = e >> 6, k = e & 63;
    WT[(size_t)(bj * 64 + j) * kC + bi * 64 + k] = f2bf(ts[k][j]);
  }
}

// ---- 2. regroup: input f32 [b][n][256] -> bf16 grouped [b][m][wgrp(128)][c(256)][8w]
__global__ __launch_bounds__(256) void regroup_kernel(const float* __restrict__ X,
                                                      ushort* __restrict__ G) {
  __shared__ ushort ls[64 * 288];  // [w(64)][m stride 18][c(16)]
  const int cb = blockIdx.x;   // 16 c-blocks of 16
  const int wb = blockIdx.y;   // 16 w-blocks of 64 windows (1024 rows)
  const int b = blockIdx.z;
  const int t = threadIdx.x;
  const float* src = X + ((size_t)b * kN + wb * 1024) * kC + cb * 16;
  const int lr = t >> 2, cg = t & 3;
  for (int rep = 0; rep < 16; ++rep) {
    int row = rep * 64 + lr;  // 0..1023
    float4 v = *reinterpret_cast<const float4*>(src + (size_t)row * kC + cg * 4);
    int w = row >> 4, m = row & 15;
    int base = w * 288 + m * 18 + cg * 4;
    uint p0 = (uint)f2bf(v.x) | ((uint)f2bf(v.y) << 16);
    uint p1 = (uint)f2bf(v.z) | ((uint)f2bf(v.w) << 16);
    *reinterpret_cast<uint*>(ls + base) = p0;
    *reinterpret_cast<uint*>(ls + base + 2) = p1;
  }
  __syncthreads();
  const int m = t >> 4, c_l = t & 15;
  const size_t gbase = ((size_t)b * 16 + m) * 128 + wb * 8;
#pragma unroll
  for (int r = 0; r < 8; ++r) {
    u16x8 v;
#pragma unroll
    for (int wl = 0; wl < 8; ++wl) v[wl] = ls[(r * 8 + wl) * 288 + m * 18 + c_l];
    *reinterpret_cast<u16x8*>(G + (gbase + r) * 2048 + (size_t)(cb * 16 + c_l) * 8) = v;
  }
}

// ---- 3. projection: W-panel preloaded in LDS once; barrier-free k-loop.
// blocks 0..511: K-mode (rt=bx>>1, jb=bx&1): tile 128 rows x 128 cols -> kg.
// blocks 512..543: Q-mode -> qf flat.
__global__ __launch_bounds__(256) void proj_kernel(
    const float* __restrict__ X, const ushort* __restrict__ WqT,
    const ushort* __restrict__ WkT, const float* __restrict__ bq,
    const float* __restrict__ bk, ushort* __restrict__ kg,
    ushort* __restrict__ qf) {
  __shared__ __align__(16) ushort smem[32768];  // 64 KB: W panel, reused by epilogue

  const int t = threadIdx.x, lane = t & 63, wv = t >> 6;
  const int bx = blockIdx.x;
  const bool kmode = bx < 512;
  int b, n0, jb;
  const ushort* WT;
  const float* bias;
  if (kmode) {
    int rt = bx >> 1; jb = bx & 1; b = rt >> 7; n0 = (rt & 127) * 128;
    WT = WkT; bias = bk;
  } else {
    int i = bx - 512; int rt = i >> 1; jb = i & 1; b = rt >> 3; n0 = (rt & 7) * 128;
    WT = WqT; bias = bq;
  }
  const int j0 = jb * 128;
  const float* Xbase = X + ((size_t)b * kN + n0) * kC;

  // Preload W panel: 128 j-rows x 256 k, XOR-swizzled 16B chunks.
  for (int rep = 0; rep < 16; ++rep) {
    int idx = rep * 256 + t;
    int jj = idx >> 5, cc = idx & 31;
    u16x8 v = *reinterpret_cast<const u16x8*>(WT + (size_t)(j0 + jj) * kC + cc * 8);
    *reinterpret_cast<u16x8*>(smem + jj * 256 + ((cc ^ (jj & 31)) << 3)) = v;
  }
  __syncthreads();

  const int lo = lane & 15, hi = lane >> 4;
  const int wr0 = (wv >> 1) * 64, wc0 = (wv & 1) * 64;
  f32x4v acc[4][4] = {};

#pragma unroll 2
  for (int s = 0; s < 8; ++s) {
    s16x8 a[4], bf[4];
#pragma unroll
    for (int fi = 0; fi < 4; ++fi) {
      const float* ap = Xbase + (size_t)(wr0 + fi * 16 + lo) * kC + s * 32 + hi * 8;
      float4 f0 = *reinterpret_cast<const float4*>(ap);
      float4 f1 = *reinterpret_cast<const float4*>(ap + 4);
      s16x8 av;
      av[0] = (short)f2bf(f0.x); av[1] = (short)f2bf(f0.y);
      av[2] = (short)f2bf(f0.z); av[3] = (short)f2bf(f0.w);
      av[4] = (short)f2bf(f1.x); av[5] = (short)f2bf(f1.y);
      av[6] = (short)f2bf(f1.z); av[7] = (short)f2bf(f1.w);
      a[fi] = av;
    }
#pragma unroll
    for (int fj = 0; fj < 4; ++fj) {
      int jl = wc0 + fj * 16 + lo;
      bf[fj] = *reinterpret_cast<const s16x8*>(
          smem + jl * 256 + (((s * 4 + hi) ^ (jl & 31)) << 3));
    }
#pragma unroll
    for (int fi = 0; fi < 4; ++fi)
#pragma unroll
      for (int fj = 0; fj < 4; ++fj)
        acc[fi][fj] = __builtin_amdgcn_mfma_f32_16x16x32_bf16(a[fi], bf[fj], acc[fi][fj], 0, 0, 0);
  }

  float bv[4];
#pragma unroll
  for (int fj = 0; fj < 4; ++fj) bv[fj] = bias[j0 + wc0 + fj * 16 + lo];

  if (kmode) {
    const int wgrp = (bx >> 1) & 127;
    // stage phi(acc) -> LDS [128 rows][128 cols] bf16, then gather to grouped kg
    __syncthreads();  // everyone done reading W
    ushort* ep = smem;
#pragma unroll
    for (int fi = 0; fi < 4; ++fi)
#pragma unroll
      for (int fj = 0; fj < 4; ++fj)
#pragma unroll
        for (int r = 0; r < 4; ++r) {
          int row = wr0 + fi * 16 + hi * 4 + r;
          int col = wc0 + fj * 16 + lo;
          ep[row * 128 + col] = f2bf(phi_act(acc[fi][fj][r] + bv[fj]));
        }
    __syncthreads();
    const int m = t >> 4, cl = t & 15;
#pragma unroll
    for (int rep = 0; rep < 8; ++rep) {
      int c = rep * 16 + cl;
      u16x8 v;
#pragma unroll
      for (int wl = 0; wl < 8; ++wl) v[wl] = ep[(wl * 16 + m) * 128 + c];
      *reinterpret_cast<u16x8*>(
          kg + (((size_t)(b * 16 + m) * 128 + wgrp) * 256 + j0 + c) * 8) = v;
    }
  } else {
#pragma unroll
    for (int fi = 0; fi < 4; ++fi)
#pragma unroll
      for (int fj = 0; fj < 4; ++fj)
#pragma unroll
        for (int r = 0; r < 4; ++r) {
          int row = n0 + wr0 + fi * 16 + hi * 4 + r;
          int col = j0 + wc0 + fj * 16 + lo;
          qf[((size_t)b * kQR + row) * kC + col] = f2bf(phi_act(acc[fi][fj][r] + bv[fj]));
        }
  }
}

// ---- 4. KV GEMM per (b,m): KVT[d][c] = sum_w kg[c][w]*xg[d][w], K=1024.
// LDS-free, barrier-free: fragments loaded directly global->VGPR (coalesced u16x8).
// 512 blocks (XCD-swizzled), 4 waves each 32x32.
__global__ __launch_bounds__(256) void kv_kernel(const ushort* __restrict__ kg,
                                                 const ushort* __restrict__ xg,
                                                 ushort* __restrict__ kvt) {
  const int t = threadIdx.x, lane = t & 63, wv = t >> 6;
  const int swz = (blockIdx.x & 7) * 64 + (blockIdx.x >> 3);
  const int bm = swz >> 4, cb = swz & 3, db = (swz >> 2) & 3;
  const int lo = lane & 15, hi = lane >> 4;
  const int c0 = cb * 64 + (wv >> 1) * 32;
  const int d0 = db * 64 + (wv & 1) * 32;
  const ushort* Ab = kg + (size_t)bm * 262144;
  const ushort* Bb = xg + (size_t)bm * 262144;

  f32x4v acc[2][2] = {};
#pragma unroll 4
  for (int s = 0; s < 32; ++s) {
    const int wg = s * 4 + hi;
    s16x8 a0 = *reinterpret_cast<const s16x8*>(Ab + ((size_t)wg * 256 + c0 + lo) * 8);
    s16x8 a1 = *reinterpret_cast<const s16x8*>(Ab + ((size_t)wg * 256 + c0 + 16 + lo) * 8);
    s16x8 b0 = *reinterpret_cast<const s16x8*>(Bb + ((size_t)wg * 256 + d0 + lo) * 8);
    s16x8 b1 = *reinterpret_cast<const s16x8*>(Bb + ((size_t)wg * 256 + d0 + 16 + lo) * 8);
    acc[0][0] = __builtin_amdgcn_mfma_f32_16x16x32_bf16(a0, b0, acc[0][0], 0, 0, 0);
    acc[0][1] = __builtin_amdgcn_mfma_f32_16x16x32_bf16(a0, b1, acc[0][1], 0, 0, 0);
    acc[1][0] = __builtin_amdgcn_mfma_f32_16x16x32_bf16(a1, b0, acc[1][0], 0, 0, 0);
    acc[1][1] = __builtin_amdgcn_mfma_f32_16x16x32_bf16(a1, b1, acc[1][1], 0, 0, 0);
  }
#pragma unroll
  for (int fi = 0; fi < 2; ++fi)
#pragma unroll
    for (int fj = 0; fj < 2; ++fj) {
      int d = d0 + fj * 16 + lo;
      int c = c0 + fi * 16 + hi * 4;
      u16x4 v = {f2bf(acc[fi][fj][0]), f2bf(acc[fi][fj][1]),
                 f2bf(acc[fi][fj][2]), f2bf(acc[fi][fj][3])};
      *reinterpret_cast<u16x4*>(kvt + ((size_t)bm * 256 + d) * 256 + c) = v;
    }
}

// ---- 5. out GEMM per (b,m): Out[qr*16+m][d] = qf[qr] . kvt[d] + p
// LDS-free k-loop (one barrier for Ps only). 512 blocks swizzled, 4 waves 64x64.
__global__ __launch_bounds__(256) void out_kernel(
    const ushort* __restrict__ qf, const ushort* __restrict__ kvt,
    const float* __restrict__ EQK, const float* __restrict__ Wp,
    const float* __restrict__ bp, float* __restrict__ Out) {
  __shared__ float Ps[128];
  const int t = threadIdx.x, lane = t & 63, wv = t >> 6;
  const int swz = (blockIdx.x & 7) * 64 + (blockIdx.x >> 3);
  const int bm = swz >> 4, qb = swz & 7, db = (swz >> 3) & 1;
  const int b = bm >> 4, mm = bm & 15;
  if (t < 128) {
    int qr = qb * 128 + t;
    const float* e = EQK + (((size_t)(b * 1024 + (qr >> 4)) * 16 + (qr & 15)) * 16 + mm) * 3;
    Ps[t] = e[0] * Wp[0] + e[1] * Wp[1] + e[2] * Wp[2] + bp[0];
  }
  __syncthreads();

  const int lo = lane & 15, hi = lane >> 4;
  const int wr0 = (wv >> 1) * 64, wc0 = (wv & 1) * 64;
  const ushort* Aq = qf + ((size_t)b * kQR + qb * 128) * kC;
  const ushort* Bk = kvt + ((size_t)bm * 256 + db * 128) * kC;

  f32x4v acc[4][4] = {};
#pragma unroll 2
  for (int s = 0; s < 8; ++s) {
    s16x8 a[4], bf[4];
#pragma unroll
    for (int fi = 0; fi < 4; ++fi)
      a[fi] = *reinterpret_cast<const s16x8*>(
          Aq + (size_t)(wr0 + fi * 16 + lo) * kC + s * 32 + hi * 8);
#pragma unroll
    for (int fj = 0; fj < 4; ++fj)
      bf[fj] = *reinterpret_cast<const s16x8*>(
          Bk + (size_t)(wc0 + fj * 16 + lo) * kC + s * 32 + hi * 8);
#pragma unroll
    for (int fi = 0; fi < 4; ++fi)
#pragma unroll
      for (int fj = 0; fj < 4; ++fj)
        acc[fi][fj] = __builtin_amdgcn_mfma_f32_16x16x32_bf16(a[fi], bf[fj], acc[fi][fj], 0, 0, 0);
  }
#pragma unroll
  for (int fi = 0; fi < 4; ++fi)
#pragma unroll
    for (int r = 0; r < 4; ++r) {
      int rowl = wr0 + fi * 16 + hi * 4 + r;
      int qr = qb * 128 + rowl;
      float p = Ps[rowl];
      size_t orow = ((size_t)b * kN + (size_t)qr * 16 + mm) * kC;
#pragma unroll
      for (int fj = 0; fj < 4; ++fj) {
        int d = db * 128 + wc0 + fj * 16 + lo;
        Out[orow + d] = acc[fi][fj][r] + p;
      }
    }
}

}  // namespace

extern "C" void kernel_launch(void* const* d_in, const int* in_sizes, int n_in,
                              void* d_out, int out_size, void* d_ws,
                              size_t ws_size, hipStream_t stream) {
  const float* input = (const float*)d_in[0];
  const float* eqk = (const float*)d_in[1];
  const float* Wq = (const float*)d_in[2];
  const float* bq = (const float*)d_in[3];
  const float* Wk = (const float*)d_in[4];
  const float* bk = (const float*)d_in[5];
  const float* Wp = (const float*)d_in[6];
  const float* bp = (const float*)d_in[7];
  float* out = (float*)d_out;

  ushort* ws = (ushort*)d_ws;
  ushort* WqT = ws;                  // 65536
  ushort* WkT = WqT + 65536;         // 65536
  ushort* xg = WkT + 65536;          // 8388608  grouped v  [bm][wgrp][c][8]
  ushort* kg = xg + 8388608;         // 8388608  grouped phi_k
  ushort* qf = kg + 8388608;         // 524288   phi_q flat [2048][256]
  ushort* kvt = qf + 524288;         // 2097152  KVT [bm][d][c]

  wt_kernel<<<dim3(4, 4, 2), 256, 0, stream>>>(Wq, Wk, WqT, WkT);
  regroup_kernel<<<dim3(16, 16, 2), 256, 0, stream>>>(input, xg);
  proj_kernel<<<dim3(544), 256, 0, stream>>>(input, WqT, WkT, bq, bk, kg, qf);
  kv_kernel<<<dim3(512), 256, 0, stream>>>(kg, xg, kvt);
  out_kernel<<<dim3(512), 256, 0, stream>>>(qf, kvt, eqk, Wp, bp, out);
}

// Round 13
// 154.412 us; speedup vs baseline: 1.1204x; 1.1204x over previous
//
#include <hip/hip_runtime.h>

typedef __attribute__((ext_vector_type(8))) short s16x8;
typedef __attribute__((ext_vector_type(8))) ushort u16x8;
typedef __attribute__((ext_vector_type(4))) ushort u16x4;
typedef __attribute__((ext_vector_type(4))) float f32x4v;

namespace {

constexpr int kB = 2;
constexpr int kN = 16384;
constexpr int kC = 256;
constexpr int kQR = 1024;

__device__ __forceinline__ ushort f2bf(float f) {
  union { float f; uint u; } v; v.f = f;
  uint u = v.u + 0x7fffu + ((v.u >> 16) & 1u);
  return (ushort)(u >> 16);
}

__device__ __forceinline__ float phi_act(float x) {
  return x > 0.f ? x + 2.f : __expf(x) + 1.f;
}

// ---- 1. weight transpose+convert: W[k][j] f32 -> WT[j][k] bf16
__global__ __launch_bounds__(256) void wt_kernel(const float* __restrict__ Wq,
                                                 const float* __restrict__ Wk,
                                                 ushort* __restrict__ WqT,
                                                 ushort* __restrict__ WkT) {
  __shared__ float ts[64][65];
  const float* W = blockIdx.z ? Wk : Wq;
  ushort* WT = blockIdx.z ? WkT : WqT;
  const int bi = blockIdx.x, bj = blockIdx.y, t = threadIdx.x;
  for (int rep = 0; rep < 16; ++rep) {
    int e = rep * 256 + t, r = e >> 6, c = e & 63;
    ts[r][c] = W[(size_t)(bi * 64 + r) * kC + bj * 64 + c];
  }
  __syncthreads();
  for (int rep = 0; rep < 16; ++rep) {
    int e = rep * 256 + t, j = e >> 6, k = e & 63;
    WT[(size_t)(bj * 64 + j) * kC + bi * 64 + k] = f2bf(ts[k][j]);
  }
}

// ---- 2. regroup: input f32 [b][n][256] -> bf16 grouped [b][m][wgrp(128)][c(256)][8w]
// fine grid (16,64,2)=2048 blocks for TLP; 16 windows (256 rows) per block.
__global__ __launch_bounds__(256) void regroup_kernel(const float* __restrict__ X,
                                                      ushort* __restrict__ G) {
  __shared__ ushort ls[16 * 288];  // [w(16)][m stride 18][c(16)]
  const int cb = blockIdx.x;   // 16 c-blocks of 16
  const int wb = blockIdx.y;   // 64 w-blocks of 16 windows
  const int b = blockIdx.z;
  const int t = threadIdx.x;
  const float* src = X + ((size_t)b * kN + wb * 256) * kC + cb * 16;
  const int lr = t >> 2, cg = t & 3;
#pragma unroll
  for (int rep = 0; rep < 4; ++rep) {
    int row = rep * 64 + lr;  // 0..255
    float4 v = *reinterpret_cast<const float4*>(src + (size_t)row * kC + cg * 4);
    int w = row >> 4, m = row & 15;
    int base = w * 288 + m * 18 + cg * 4;
    uint p0 = (uint)f2bf(v.x) | ((uint)f2bf(v.y) << 16);
    uint p1 = (uint)f2bf(v.z) | ((uint)f2bf(v.w) << 16);
    *reinterpret_cast<uint*>(ls + base) = p0;
    *reinterpret_cast<uint*>(ls + base + 2) = p1;
  }
  __syncthreads();
  const int m = t >> 4, c_l = t & 15;
#pragma unroll
  for (int oct = 0; oct < 2; ++oct) {
    u16x8 v;
#pragma unroll
    for (int wl = 0; wl < 8; ++wl) v[wl] = ls[(oct * 8 + wl) * 288 + m * 18 + c_l];
    *reinterpret_cast<u16x8*>(
        G + (((size_t)(b * 16 + m) * 128 + wb * 2 + oct) * 256 + cb * 16 + c_l) * 8) = v;
  }
}

// ---- 3. projection: tile 64 rows x 128 j. W-panel (128x256) preloaded in LDS once;
// A-tile (64x32) LDS double-buffered with coalesced float4 staging. Grid 1088.
__global__ __launch_bounds__(256) void proj_kernel(
    const float* __restrict__ X, const ushort* __restrict__ WqT,
    const ushort* __restrict__ WkT, const float* __restrict__ bq,
    const float* __restrict__ bk, ushort* __restrict__ kg,
    ushort* __restrict__ qf) {
  __shared__ __align__(16) ushort smem[36864];  // 72KB: W 64KB + A dbuf 2x4KB

  const int t = threadIdx.x, lane = t & 63, wv = t >> 6;
  const int bx = blockIdx.x;
  const bool kmode = bx < 1024;
  int b, n0, jb;
  const ushort* WT;
  const float* bias;
  if (kmode) {
    b = bx >> 9; int rem = bx & 511; n0 = (rem >> 1) * 64; jb = bx & 1;
    WT = WkT; bias = bk;
  } else {
    int i = bx - 1024; b = i >> 5; int rem = i & 31; n0 = (rem >> 1) * 64; jb = i & 1;
    WT = WqT; bias = bq;
  }
  const int j0 = jb * 128;
  const float* Xb = X + ((size_t)b * kN + n0) * kC;

  // W preload: [128 j][256 k] bf16, chunk swizzle cc ^= (j&31)
  for (int rep = 0; rep < 16; ++rep) {
    int idx = rep * 256 + t;
    int jj = idx >> 5, cc = idx & 31;
    u16x8 v = *reinterpret_cast<const u16x8*>(WT + (size_t)(j0 + jj) * kC + cc * 8);
    *reinterpret_cast<u16x8*>(smem + jj * 256 + ((cc ^ (jj & 31)) << 3)) = v;
  }

  // A stage: coalesced — 8 lanes per row (quad aq), rows ar and ar+32
  const int aq = t & 7, ar = t >> 3;
  float4 fa0, fa1;
  auto aLoad = [&](int s) {
    fa0 = *reinterpret_cast<const float4*>(Xb + (size_t)ar * kC + s * 32 + aq * 4);
    fa1 = *reinterpret_cast<const float4*>(Xb + (size_t)(ar + 32) * kC + s * 32 + aq * 4);
  };
  auto aWrite = [&](int h) {
    ushort* A = smem + 32768 + h * 2048;
    u16x4 v0 = {f2bf(fa0.x), f2bf(fa0.y), f2bf(fa0.z), f2bf(fa0.w)};
    u16x4 v1 = {f2bf(fa1.x), f2bf(fa1.y), f2bf(fa1.z), f2bf(fa1.w)};
    *reinterpret_cast<u16x4*>(A + ar * 32 + (((aq >> 1) ^ ((ar >> 1) & 3)) << 3) +
                              (aq & 1) * 4) = v0;
    const int r1 = ar + 32;
    *reinterpret_cast<u16x4*>(A + r1 * 32 + (((aq >> 1) ^ ((r1 >> 1) & 3)) << 3) +
                              (aq & 1) * 4) = v1;
  };

  const int lo = lane & 15, hi = lane >> 4;
  const int wr0 = (wv >> 1) * 32, wc0 = (wv & 1) * 64;
  f32x4v acc[2][4] = {};
  auto mma = [&](int h, int s) {
    const ushort* A = smem + 32768 + h * 2048;
    s16x8 a[2], bf[4];
#pragma unroll
    for (int i = 0; i < 2; ++i) {
      int r = wr0 + i * 16 + lo;
      a[i] = *reinterpret_cast<const s16x8*>(A + r * 32 + ((hi ^ ((r >> 1) & 3)) << 3));
    }
#pragma unroll
    for (int fj = 0; fj < 4; ++fj) {
      int j = wc0 + fj * 16 + lo;
      bf[fj] = *reinterpret_cast<const s16x8*>(
          smem + j * 256 + (((s * 4 + hi) ^ (j & 31)) << 3));
    }
#pragma unroll
    for (int i = 0; i < 2; ++i)
#pragma unroll
      for (int fj = 0; fj < 4; ++fj)
        acc[i][fj] = __builtin_amdgcn_mfma_f32_16x16x32_bf16(a[i], bf[fj], acc[i][fj], 0, 0, 0);
  };

  aLoad(0);
  aWrite(0);
  __syncthreads();
  int cur = 0;
  for (int s = 0; s < 8; ++s) {
    if (s < 7) aLoad(s + 1);
    __builtin_amdgcn_sched_barrier(0);
    mma(cur, s);
    __builtin_amdgcn_sched_barrier(0);
    if (s < 7) aWrite(cur ^ 1);
    __syncthreads();
    cur ^= 1;
  }

  float bv[4];
#pragma unroll
  for (int fj = 0; fj < 4; ++fj) bv[fj] = bias[j0 + wc0 + fj * 16 + lo];

  if (kmode) {
    // epilogue: phi -> LDS [64 rows][128 cols] (reuse W region), gather to kg
    __syncthreads();
    ushort* ep = smem;
#pragma unroll
    for (int i = 0; i < 2; ++i)
#pragma unroll
      for (int fj = 0; fj < 4; ++fj)
#pragma unroll
        for (int r = 0; r < 4; ++r) {
          int row = wr0 + i * 16 + hi * 4 + r;
          int col = wc0 + fj * 16 + lo;
          ep[row * 128 + col] = f2bf(phi_act(acc[i][fj][r] + bv[fj]));
        }
    __syncthreads();
    const int m = t >> 4, cl = t & 15;
    const int wgrp = n0 >> 7, sub = (n0 >> 6) & 1;
#pragma unroll
    for (int rep = 0; rep < 8; ++rep) {
      int c = rep * 16 + cl;
      u16x4 v;
#pragma unroll
      for (int wl = 0; wl < 4; ++wl) v[wl] = ep[(wl * 16 + m) * 128 + c];
      *reinterpret_cast<u16x4*>(
          kg + (((size_t)(b * 16 + m) * 128 + wgrp) * 256 + j0 + c) * 8 + sub * 4) = v;
    }
  } else {
#pragma unroll
    for (int i = 0; i < 2; ++i)
#pragma unroll
      for (int fj = 0; fj < 4; ++fj)
#pragma unroll
        for (int r = 0; r < 4; ++r) {
          int row = n0 + wr0 + i * 16 + hi * 4 + r;
          int col = j0 + wc0 + fj * 16 + lo;
          qf[((size_t)b * kQR + row) * kC + col] = f2bf(phi_act(acc[i][fj][r] + bv[fj]));
        }
  }
}

// ---- 4. KV GEMM per (b,m): KVT[d][c] = sum_w kg[c][w]*xg[d][w], K=1024.
// tile 64x64, BK=128 (8 steps, long compute per step), dbuf LDS 64KB, XCD swizzle.
__global__ __launch_bounds__(256) void kv_kernel(const ushort* __restrict__ kg,
                                                 const ushort* __restrict__ xg,
                                                 ushort* __restrict__ kvt) {
  __shared__ __align__(16) ushort smem[32768];  // A dbuf 2x8192, B dbuf 2x8192
  const int t = threadIdx.x, lane = t & 63, wv = t >> 6;
  const int swz = (blockIdx.x & 7) * 64 + (blockIdx.x >> 3);
  const int bm = swz >> 4, cb = swz & 3, db = (swz >> 2) & 3;
  const int lc = t & 63, g = t >> 6;
  const ushort* Ab = kg + (size_t)bm * 262144 + (size_t)(cb * 64 + lc) * 8;
  const ushort* Bb = xg + (size_t)bm * 262144 + (size_t)(db * 64 + lc) * 8;

  u16x8 ra[4], rb[4];
  auto sLoad = [&](int s) {
#pragma unroll
    for (int q = 0; q < 4; ++q) {
      const size_t w8 = (size_t)(s * 16 + g + q * 4) * 2048;
      ra[q] = *reinterpret_cast<const u16x8*>(Ab + w8);
      rb[q] = *reinterpret_cast<const u16x8*>(Bb + w8);
    }
  };
  auto sWrite = [&](int h) {
    ushort* A = smem + h * 8192;
    ushort* B = smem + 16384 + h * 8192;
    const int fl = (lc & 15) ^ (lc >> 4);
#pragma unroll
    for (int q = 0; q < 4; ++q) {
      int o = g + q * 4;
      *reinterpret_cast<u16x8*>(A + lc * 128 + ((o ^ fl) << 3)) = ra[q];
      *reinterpret_cast<u16x8*>(B + lc * 128 + ((o ^ fl) << 3)) = rb[q];
    }
  };

  const int lo = lane & 15, hi = lane >> 4;
  const int wr0 = (wv >> 1) * 32, wc0 = (wv & 1) * 32;
  f32x4v acc[2][2] = {};
  auto mma = [&](int h) {
    const ushort* A = smem + h * 8192;
    const ushort* B = smem + 16384 + h * 8192;
#pragma unroll
    for (int kk = 0; kk < 4; ++kk) {
      s16x8 a0, a1, b0, b1;
      {
        int r = wr0 + lo;
        a0 = *reinterpret_cast<const s16x8*>(
            A + r * 128 + (((kk * 4 + hi) ^ ((r & 15) ^ (r >> 4))) << 3));
        int r2 = wr0 + 16 + lo;
        a1 = *reinterpret_cast<const s16x8*>(
            A + r2 * 128 + (((kk * 4 + hi) ^ ((r2 & 15) ^ (r2 >> 4))) << 3));
        int c = wc0 + lo;
        b0 = *reinterpret_cast<const s16x8*>(
            B + c * 128 + (((kk * 4 + hi) ^ ((c & 15) ^ (c >> 4))) << 3));
        int c2 = wc0 + 16 + lo;
        b1 = *reinterpret_cast<const s16x8*>(
            B + c2 * 128 + (((kk * 4 + hi) ^ ((c2 & 15) ^ (c2 >> 4))) << 3));
      }
      acc[0][0] = __builtin_amdgcn_mfma_f32_16x16x32_bf16(a0, b0, acc[0][0], 0, 0, 0);
      acc[0][1] = __builtin_amdgcn_mfma_f32_16x16x32_bf16(a0, b1, acc[0][1], 0, 0, 0);
      acc[1][0] = __builtin_amdgcn_mfma_f32_16x16x32_bf16(a1, b0, acc[1][0], 0, 0, 0);
      acc[1][1] = __builtin_amdgcn_mfma_f32_16x16x32_bf16(a1, b1, acc[1][1], 0, 0, 0);
    }
  };

  sLoad(0);
  sWrite(0);
  __syncthreads();
  int cur = 0;
  for (int s = 0; s < 8; ++s) {
    if (s < 7) sLoad(s + 1);
    __builtin_amdgcn_sched_barrier(0);
    mma(cur);
    __builtin_amdgcn_sched_barrier(0);
    if (s < 7) sWrite(cur ^ 1);
    __syncthreads();
    cur ^= 1;
  }
#pragma unroll
  for (int fi = 0; fi < 2; ++fi)
#pragma unroll
    for (int fj = 0; fj < 2; ++fj) {
      int d = db * 64 + wc0 + fj * 16 + lo;
      int c = cb * 64 + wr0 + fi * 16 + hi * 4;
      u16x4 v = {f2bf(acc[fi][fj][0]), f2bf(acc[fi][fj][1]),
                 f2bf(acc[fi][fj][2]), f2bf(acc[fi][fj][3])};
      *reinterpret_cast<u16x4*>(kvt + ((size_t)bm * 256 + d) * 256 + c) = v;
    }
}

// ---- 5. out GEMM per (b,m): Out[qr*16+m][d] = qf[qr] . kvt[d] + p  (R9 form)
__global__ __launch_bounds__(256) void out_kernel(
    const ushort* __restrict__ qf, const ushort* __restrict__ kvt,
    const float* __restrict__ EQK, const float* __restrict__ Wp,
    const float* __restrict__ bp, float* __restrict__ Out) {
  __shared__ __align__(16) ushort smem[16384];
  __shared__ float Ps[128];
  const int t = threadIdx.x, lane = t & 63, wv = t >> 6;
  const int swz = (blockIdx.x & 7) * 64 + (blockIdx.x >> 3);
  const int bm = swz >> 4, qb = swz & 7, db = (swz >> 3) & 1;
  const int b = bm >> 4, mm = bm & 15;
  if (t < 128) {
    int qr = qb * 128 + t;
    const float* e = EQK + (((size_t)(b * 1024 + (qr >> 4)) * 16 + (qr & 15)) * 16 + mm) * 3;
    Ps[t] = e[0] * Wp[0] + e[1] * Wp[1] + e[2] * Wp[2] + bp[0];
  }
  const int r2 = t >> 2, ch = t & 3;

  u16x8 ra0, ra1, rb0, rb1;
  auto stageLoad = [&](int ks) {
    int k0 = ks * 32;
    const ushort* Aq = qf + ((size_t)b * kQR + qb * 128) * kC;
    const ushort* Bk = kvt + ((size_t)bm * 256 + db * 128) * kC;
    ra0 = *reinterpret_cast<const u16x8*>(Aq + (size_t)r2 * kC + k0 + ch * 8);
    ra1 = *reinterpret_cast<const u16x8*>(Aq + (size_t)(r2 + 64) * kC + k0 + ch * 8);
    rb0 = *reinterpret_cast<const u16x8*>(Bk + (size_t)r2 * kC + k0 + ch * 8);
    rb1 = *reinterpret_cast<const u16x8*>(Bk + (size_t)(r2 + 64) * kC + k0 + ch * 8);
  };
  auto stageWrite = [&](int h) {
    ushort* A = smem + h * 4096;
    ushort* B = smem + 8192 + h * 4096;
    *reinterpret_cast<u16x8*>(A + r2 * 32 + ((ch ^ ((r2 >> 1) & 3)) << 3)) = ra0;
    *reinterpret_cast<u16x8*>(A + (r2 + 64) * 32 + ((ch ^ (((r2 + 64) >> 1) & 3)) << 3)) = ra1;
    *reinterpret_cast<u16x8*>(B + r2 * 32 + ((ch ^ ((r2 >> 1) & 3)) << 3)) = rb0;
    *reinterpret_cast<u16x8*>(B + (r2 + 64) * 32 + ((ch ^ (((r2 + 64) >> 1) & 3)) << 3)) = rb1;
  };

  f32x4v acc[4][4] = {};
  const int lo = lane & 15, hi = lane >> 4;
  const int wr0 = (wv >> 1) * 64, wc0 = (wv & 1) * 64;
  auto mma = [&](int h) {
    const ushort* A = smem + h * 4096;
    const ushort* B = smem + 8192 + h * 4096;
    s16x8 af[4], bf[4];
#pragma unroll
    for (int i = 0; i < 4; ++i) {
      int r = wr0 + i * 16 + lo;
      af[i] = *reinterpret_cast<const s16x8*>(A + r * 32 + ((hi ^ ((r >> 1) & 3)) << 3));
    }
#pragma unroll
    for (int j = 0; j < 4; ++j) {
      int c = wc0 + j * 16 + lo;
      bf[j] = *reinterpret_cast<const s16x8*>(B + c * 32 + ((hi ^ ((c >> 1) & 3)) << 3));
    }
#pragma unroll
    for (int i = 0; i < 4; ++i)
#pragma unroll
      for (int j = 0; j < 4; ++j)
        acc[i][j] = __builtin_amdgcn_mfma_f32_16x16x32_bf16(af[i], bf[j], acc[i][j], 0, 0, 0);
  };

  stageLoad(0);
  stageWrite(0);
  __syncthreads();
  int cur = 0;
  for (int ks = 0; ks < 8; ++ks) {
    if (ks < 7) stageLoad(ks + 1);
    __builtin_amdgcn_sched_barrier(0);
    mma(cur);
    __builtin_amdgcn_sched_barrier(0);
    if (ks < 7) stageWrite(cur ^ 1);
    __syncthreads();
    cur ^= 1;
  }
#pragma unroll
  for (int fi = 0; fi < 4; ++fi)
#pragma unroll
    for (int r4 = 0; r4 < 4; ++r4) {
      int rowl = wr0 + fi * 16 + hi * 4 + r4;
      int qr = qb * 128 + rowl;
      float p = Ps[rowl];
      size_t orow = ((size_t)b * kN + (size_t)qr * 16 + mm) * kC;
#pragma unroll
      for (int fj = 0; fj < 4; ++fj) {
        int d = db * 128 + wc0 + fj * 16 + lo;
        Out[orow + d] = acc[fi][fj][r4] + p;
      }
    }
}

}  // namespace

extern "C" void kernel_launch(void* const* d_in, const int* in_sizes, int n_in,
                              void* d_out, int out_size, void* d_ws,
                              size_t ws_size, hipStream_t stream) {
  const float* input = (const float*)d_in[0];
  const float* eqk = (const float*)d_in[1];
  const float* Wq = (const float*)d_in[2];
  const float* bq = (const float*)d_in[3];
  const float* Wk = (const float*)d_in[4];
  const float* bk = (const float*)d_in[5];
  const float* Wp = (const float*)d_in[6];
  const float* bp = (const float*)d_in[7];
  float* out = (float*)d_out;

  ushort* ws = (ushort*)d_ws;
  ushort* WqT = ws;                  // 65536
  ushort* WkT = WqT + 65536;         // 65536
  ushort* xg = WkT + 65536;          // 8388608  grouped v  [bm][wgrp][c][8]
  ushort* kg = xg + 8388608;         // 8388608  grouped phi_k
  ushort* qf = kg + 8388608;         // 524288   phi_q flat [2048][256]
  ushort* kvt = qf + 524288;         // 2097152  KVT [bm][d][c]

  wt_kernel<<<dim3(4, 4, 2), 256, 0, stream>>>(Wq, Wk, WqT, WkT);
  regroup_kernel<<<dim3(16, 64, 2), 256, 0, stream>>>(input, xg);
  proj_kernel<<<dim3(1088), 256, 0, stream>>>(input, WqT, WkT, bq, bk, kg, qf);
  kv_kernel<<<dim3(512), 256, 0, stream>>>(kg, xg, kvt);
  out_kernel<<<dim3(512), 256, 0, stream>>>(qf, kvt, eqk, Wp, bp, out);
}

// Round 14
// 153.961 us; speedup vs baseline: 1.1237x; 1.0029x over previous
//
#include <hip/hip_runtime.h>

typedef __attribute__((ext_vector_type(8))) short s16x8;
typedef __attribute__((ext_vector_type(8))) ushort u16x8;
typedef __attribute__((ext_vector_type(4))) ushort u16x4;
typedef __attribute__((ext_vector_type(4))) float f32x4v;

namespace {

constexpr int kB = 2;
constexpr int kN = 16384;
constexpr int kC = 256;
constexpr int kQR = 1024;

__device__ __forceinline__ ushort f2bf(float f) {
  union { float f; uint u; } v; v.f = f;
  uint u = v.u + 0x7fffu + ((v.u >> 16) & 1u);
  return (ushort)(u >> 16);
}

__device__ __forceinline__ float phi_act(float x) {
  return x > 0.f ? x + 2.f : __expf(x) + 1.f;
}

// global -> LDS direct copy, 16 bytes per lane. LDS dest must be linear in
// lane order (HW uses wave-uniform base + lane*16); swizzles go on the SOURCE.
__device__ __forceinline__ void gl16(const ushort* g, ushort* l) {
  __builtin_amdgcn_global_load_lds(
      (const __attribute__((address_space(1))) void*)g,
      (__attribute__((address_space(3))) void*)l, 16, 0, 0);
}

// ---- 1. weight transpose+convert: W[k][j] f32 -> WT[j][k] bf16
__global__ __launch_bounds__(256) void wt_kernel(const float* __restrict__ Wq,
                                                 const float* __restrict__ Wk,
                                                 ushort* __restrict__ WqT,
                                                 ushort* __restrict__ WkT) {
  __shared__ float ts[64][65];
  const float* W = blockIdx.z ? Wk : Wq;
  ushort* WT = blockIdx.z ? WkT : WqT;
  const int bi = blockIdx.x, bj = blockIdx.y, t = threadIdx.x;
  for (int rep = 0; rep < 16; ++rep) {
    int e = rep * 256 + t, r = e >> 6, c = e & 63;
    ts[r][c] = W[(size_t)(bi * 64 + r) * kC + bj * 64 + c];
  }
  __syncthreads();
  for (int rep = 0; rep < 16; ++rep) {
    int e = rep * 256 + t, j = e >> 6, k = e & 63;
    WT[(size_t)(bj * 64 + j) * kC + bi * 64 + k] = f2bf(ts[k][j]);
  }
}

// ---- 2. regroup: input f32 [b][n][256] -> bf16 grouped [b][m][w8(128)][c(256)][8w]
__global__ __launch_bounds__(256) void regroup_kernel(const float* __restrict__ X,
                                                      ushort* __restrict__ G) {
  __shared__ ushort ls[16 * 288];
  const int cb = blockIdx.x;   // 16 c-blocks of 16
  const int wb = blockIdx.y;   // 64 w-blocks of 16 windows
  const int b = blockIdx.z;
  const int t = threadIdx.x;
  const float* src = X + ((size_t)b * kN + wb * 256) * kC + cb * 16;
  const int lr = t >> 2, cg = t & 3;
#pragma unroll
  for (int rep = 0; rep < 4; ++rep) {
    int row = rep * 64 + lr;
    float4 v = *reinterpret_cast<const float4*>(src + (size_t)row * kC + cg * 4);
    int w = row >> 4, m = row & 15;
    int base = w * 288 + m * 18 + cg * 4;
    uint p0 = (uint)f2bf(v.x) | ((uint)f2bf(v.y) << 16);
    uint p1 = (uint)f2bf(v.z) | ((uint)f2bf(v.w) << 16);
    *reinterpret_cast<uint*>(ls + base) = p0;
    *reinterpret_cast<uint*>(ls + base + 2) = p1;
  }
  __syncthreads();
  const int m = t >> 4, c_l = t & 15;
#pragma unroll
  for (int oct = 0; oct < 2; ++oct) {
    u16x8 v;
#pragma unroll
    for (int wl = 0; wl < 8; ++wl) v[wl] = ls[(oct * 8 + wl) * 288 + m * 18 + c_l];
    *reinterpret_cast<u16x8*>(
        G + (((size_t)(b * 16 + m) * 128 + wb * 2 + oct) * 256 + cb * 16 + c_l) * 8) = v;
  }
}

// ---- 3. projection: tile 64 rows x 128 j. W preloaded via gl16 (src-swizzled);
// A-tile reg-staged (f32->bf16 cvt) dbuf. Grid 1088.
__global__ __launch_bounds__(256) void proj_kernel(
    const float* __restrict__ X, const ushort* __restrict__ WqT,
    const ushort* __restrict__ WkT, const float* __restrict__ bq,
    const float* __restrict__ bk, ushort* __restrict__ kg,
    ushort* __restrict__ qf) {
  __shared__ __align__(16) ushort smem[36864];  // 72KB: W 64KB + A dbuf 2x4KB

  const int t = threadIdx.x, lane = t & 63, wv = t >> 6;
  const int bx = blockIdx.x;
  const bool kmode = bx < 1024;
  int b, n0, jb;
  const ushort* WT;
  const float* bias;
  if (kmode) {
    b = bx >> 9; int rem = bx & 511; n0 = (rem >> 1) * 64; jb = bx & 1;
    WT = WkT; bias = bk;
  } else {
    int i = bx - 1024; b = i >> 5; int rem = i & 31; n0 = (rem >> 1) * 64; jb = i & 1;
    WT = WqT; bias = bq;
  }
  const int j0 = jb * 128;
  const float* Xb = X + ((size_t)b * kN + n0) * kC;

  // W preload via global_load_lds: LDS linear [j][32 chunks]; source chunk
  // pre-swizzled cc^(jj&31) so reads (unchanged) are conflict-free.
  for (int rep = 0; rep < 16; ++rep) {
    int idx = rep * 256 + t;
    int jj = idx >> 5, cc = idx & 31;
    gl16(WT + (size_t)(j0 + jj) * kC + (size_t)(cc ^ (jj & 31)) * 8,
         smem + idx * 8);
  }

  const int aq = t & 7, ar = t >> 3;
  float4 fa0, fa1;
  auto aLoad = [&](int s) {
    fa0 = *reinterpret_cast<const float4*>(Xb + (size_t)ar * kC + s * 32 + aq * 4);
    fa1 = *reinterpret_cast<const float4*>(Xb + (size_t)(ar + 32) * kC + s * 32 + aq * 4);
  };
  auto aWrite = [&](int h) {
    ushort* A = smem + 32768 + h * 2048;
    u16x4 v0 = {f2bf(fa0.x), f2bf(fa0.y), f2bf(fa0.z), f2bf(fa0.w)};
    u16x4 v1 = {f2bf(fa1.x), f2bf(fa1.y), f2bf(fa1.z), f2bf(fa1.w)};
    *reinterpret_cast<u16x4*>(A + ar * 32 + (((aq >> 1) ^ ((ar >> 1) & 3)) << 3) +
                              (aq & 1) * 4) = v0;
    const int r1 = ar + 32;
    *reinterpret_cast<u16x4*>(A + r1 * 32 + (((aq >> 1) ^ ((r1 >> 1) & 3)) << 3) +
                              (aq & 1) * 4) = v1;
  };

  const int lo = lane & 15, hi = lane >> 4;
  const int wr0 = (wv >> 1) * 32, wc0 = (wv & 1) * 64;
  f32x4v acc[2][4] = {};
  auto mma = [&](int h, int s) {
    const ushort* A = smem + 32768 + h * 2048;
    s16x8 a[2], bf[4];
#pragma unroll
    for (int i = 0; i < 2; ++i) {
      int r = wr0 + i * 16 + lo;
      a[i] = *reinterpret_cast<const s16x8*>(A + r * 32 + ((hi ^ ((r >> 1) & 3)) << 3));
    }
#pragma unroll
    for (int fj = 0; fj < 4; ++fj) {
      int j = wc0 + fj * 16 + lo;
      bf[fj] = *reinterpret_cast<const s16x8*>(
          smem + j * 256 + (((s * 4 + hi) ^ (j & 31)) << 3));
    }
#pragma unroll
    for (int i = 0; i < 2; ++i)
#pragma unroll
      for (int fj = 0; fj < 4; ++fj)
        acc[i][fj] = __builtin_amdgcn_mfma_f32_16x16x32_bf16(a[i], bf[fj], acc[i][fj], 0, 0, 0);
  };

  aLoad(0);
  aWrite(0);
  __syncthreads();  // drains gl16 (vmcnt) + ds_writes
  int cur = 0;
  for (int s = 0; s < 8; ++s) {
    if (s < 7) aLoad(s + 1);
    __builtin_amdgcn_sched_barrier(0);
    mma(cur, s);
    __builtin_amdgcn_sched_barrier(0);
    if (s < 7) aWrite(cur ^ 1);
    __syncthreads();
    cur ^= 1;
  }

  float bv[4];
#pragma unroll
  for (int fj = 0; fj < 4; ++fj) bv[fj] = bias[j0 + wc0 + fj * 16 + lo];

  if (kmode) {
    __syncthreads();
    ushort* ep = smem;
#pragma unroll
    for (int i = 0; i < 2; ++i)
#pragma unroll
      for (int fj = 0; fj < 4; ++fj)
#pragma unroll
        for (int r = 0; r < 4; ++r) {
          int row = wr0 + i * 16 + hi * 4 + r;
          int col = wc0 + fj * 16 + lo;
          ep[row * 128 + col] = f2bf(phi_act(acc[i][fj][r] + bv[fj]));
        }
    __syncthreads();
    const int m = t >> 4, cl = t & 15;
    const int wgrp = n0 >> 7, sub = (n0 >> 6) & 1;
#pragma unroll
    for (int rep = 0; rep < 8; ++rep) {
      int c = rep * 16 + cl;
      u16x4 v;
#pragma unroll
      for (int wl = 0; wl < 4; ++wl) v[wl] = ep[(wl * 16 + m) * 128 + c];
      *reinterpret_cast<u16x4*>(
          kg + (((size_t)(b * 16 + m) * 128 + wgrp) * 256 + j0 + c) * 8 + sub * 4) = v;
    }
  } else {
#pragma unroll
    for (int i = 0; i < 2; ++i)
#pragma unroll
      for (int fj = 0; fj < 4; ++fj)
#pragma unroll
        for (int r = 0; r < 4; ++r) {
          int row = n0 + wr0 + i * 16 + hi * 4 + r;
          int col = j0 + wc0 + fj * 16 + lo;
          qf[((size_t)b * kQR + row) * kC + col] = f2bf(phi_act(acc[i][fj][r] + bv[fj]));
        }
  }
}

// ---- 4. KV GEMM per (b,m): KVT[d][c] = sum_w kg[c][w]*xg[d][w], K=1024.
// Chunk-major LDS [o=16][c=64][8h] filled by gl16: wave loads 1KB contiguous,
// LDS dest linear, fragment reads conflict-free with NO swizzle. BK=128, 8 steps.
__global__ __launch_bounds__(256) void kv_kernel(const ushort* __restrict__ kg,
                                                 const ushort* __restrict__ xg,
                                                 ushort* __restrict__ kvt) {
  __shared__ __align__(16) ushort smem[32768];  // 64KB: A[2][16][64][8], B[2][16][64][8]
  const int t = threadIdx.x, lane = t & 63, wv = t >> 6;
  const int swz = (blockIdx.x & 7) * 64 + (blockIdx.x >> 3);
  const int bm = swz >> 4, cb = swz & 3, db = (swz >> 2) & 3;
  const int c_l = t & 63;
  const ushort* Abase = kg + (size_t)bm * 262144 + (size_t)(cb * 64) * 8;
  const ushort* Bbase = xg + (size_t)bm * 262144 + (size_t)(db * 64) * 8;

  auto STAGE = [&](int h, int s) {
    ushort* A = smem + h * 8192;
    ushort* B = smem + 16384 + h * 8192;
#pragma unroll
    for (int i = 0; i < 4; ++i) {
      int o = i * 4 + wv;  // wave-uniform chunk
      size_t goff = ((size_t)(s * 16 + o) * 256 + c_l) * 8;
      int loff = (i * 256 + t) * 8;  // linear: lane*16B within wave
      gl16(Abase + goff, A + loff);
      gl16(Bbase + goff, B + loff);
    }
  };

  const int lo = lane & 15, hi = lane >> 4;
  const int wr0 = (wv >> 1) * 32, wc0 = (wv & 1) * 32;
  f32x4v acc[2][2] = {};
  auto MMA = [&](int h) {
    const ushort* A = smem + h * 8192;
    const ushort* B = smem + 16384 + h * 8192;
#pragma unroll
    for (int kk = 0; kk < 4; ++kk) {
      const int o = kk * 4 + hi;
      s16x8 a0 = *reinterpret_cast<const s16x8*>(A + o * 512 + (wr0 + lo) * 8);
      s16x8 a1 = *reinterpret_cast<const s16x8*>(A + o * 512 + (wr0 + 16 + lo) * 8);
      s16x8 b0 = *reinterpret_cast<const s16x8*>(B + o * 512 + (wc0 + lo) * 8);
      s16x8 b1 = *reinterpret_cast<const s16x8*>(B + o * 512 + (wc0 + 16 + lo) * 8);
      acc[0][0] = __builtin_amdgcn_mfma_f32_16x16x32_bf16(a0, b0, acc[0][0], 0, 0, 0);
      acc[0][1] = __builtin_amdgcn_mfma_f32_16x16x32_bf16(a0, b1, acc[0][1], 0, 0, 0);
      acc[1][0] = __builtin_amdgcn_mfma_f32_16x16x32_bf16(a1, b0, acc[1][0], 0, 0, 0);
      acc[1][1] = __builtin_amdgcn_mfma_f32_16x16x32_bf16(a1, b1, acc[1][1], 0, 0, 0);
    }
  };

  STAGE(0, 0);
  __syncthreads();  // vmcnt(0) drain -> buf0 ready
  int cur = 0;
  for (int s = 0; s < 8; ++s) {
    if (s < 7) STAGE(cur ^ 1, s + 1);
    __builtin_amdgcn_sched_barrier(0);
    MMA(cur);
    __syncthreads();
    cur ^= 1;
  }
#pragma unroll
  for (int fi = 0; fi < 2; ++fi)
#pragma unroll
    for (int fj = 0; fj < 2; ++fj) {
      int d = db * 64 + wc0 + fj * 16 + lo;
      int c = cb * 64 + wr0 + fi * 16 + hi * 4;
      u16x4 v = {f2bf(acc[fi][fj][0]), f2bf(acc[fi][fj][1]),
                 f2bf(acc[fi][fj][2]), f2bf(acc[fi][fj][3])};
      *reinterpret_cast<u16x4*>(kvt + ((size_t)bm * 256 + d) * 256 + c) = v;
    }
}

// ---- 5. out GEMM per (b,m): Out[qr*16+m][d] = qf[qr].kvt[d] + p.
// Full-K panels staged ONCE via gl16 (src chunk-swizzled), zero loop barriers.
__global__ __launch_bounds__(256) void out_kernel(
    const ushort* __restrict__ qf, const ushort* __restrict__ kvt,
    const float* __restrict__ EQK, const float* __restrict__ Wp,
    const float* __restrict__ bp, float* __restrict__ Out) {
  __shared__ __align__(16) ushort smem[65536];  // 128KB: A 64KB | B 64KB
  __shared__ float Ps[128];
  const int t = threadIdx.x, lane = t & 63, wv = t >> 6;
  const int swz = (blockIdx.x & 7) * 64 + (blockIdx.x >> 3);
  const int bm = swz >> 4, qb = swz & 7, db = (swz >> 3) & 1;
  const int b = bm >> 4, mm = bm & 15;
  if (t < 128) {
    int qr = qb * 128 + t;
    const float* e = EQK + (((size_t)(b * 1024 + (qr >> 4)) * 16 + (qr & 15)) * 16 + mm) * 3;
    Ps[t] = e[0] * Wp[0] + e[1] * Wp[1] + e[2] * Wp[2] + bp[0];
  }
  const ushort* Aq = qf + ((size_t)b * kQR + qb * 128) * kC;
  const ushort* Bk = kvt + ((size_t)bm * 256 + db * 128) * kC;

  // stage: LDS [r=128][o=32][8h] linear; source chunk low-3-bits XOR r
  // (involution) so ds_read_b128 with the same XOR is 2-way (free).
#pragma unroll
  for (int i = 0; i < 16; ++i) {
    int S = i * 256 + t;
    int r = S >> 5, o = S & 31;
    int osrc = (o & 24) | ((o & 7) ^ (r & 7));
    gl16(Aq + (size_t)r * kC + osrc * 8, smem + S * 8);
    gl16(Bk + (size_t)r * kC + osrc * 8, smem + 32768 + S * 8);
  }
  __syncthreads();  // single drain: both panels ready

  const int lo = lane & 15, hi = lane >> 4;
  const int wr0 = (wv >> 1) * 64, wc0 = (wv & 1) * 64;
  f32x4v acc[4][4] = {};
#pragma unroll
  for (int kk = 0; kk < 8; ++kk) {
    const int j = kk * 4 + hi;
    s16x8 a[4], bf[4];
#pragma unroll
    for (int fi = 0; fi < 4; ++fi) {
      int r = wr0 + fi * 16 + lo;
      int o = (j & 24) | ((j & 7) ^ (r & 7));
      a[fi] = *reinterpret_cast<const s16x8*>(smem + r * 256 + o * 8);
    }
#pragma unroll
    for (int fj = 0; fj < 4; ++fj) {
      int r = wc0 + fj * 16 + lo;
      int o = (j & 24) | ((j & 7) ^ (r & 7));
      bf[fj] = *reinterpret_cast<const s16x8*>(smem + 32768 + r * 256 + o * 8);
    }
#pragma unroll
    for (int fi = 0; fi < 4; ++fi)
#pragma unroll
      for (int fj = 0; fj < 4; ++fj)
        acc[fi][fj] = __builtin_amdgcn_mfma_f32_16x16x32_bf16(a[fi], bf[fj], acc[fi][fj], 0, 0, 0);
  }
#pragma unroll
  for (int fi = 0; fi < 4; ++fi)
#pragma unroll
    for (int r4 = 0; r4 < 4; ++r4) {
      int rowl = wr0 + fi * 16 + hi * 4 + r4;
      int qr = qb * 128 + rowl;
      float p = Ps[rowl];
      size_t orow = ((size_t)b * kN + (size_t)qr * 16 + mm) * kC;
#pragma unroll
      for (int fj = 0; fj < 4; ++fj) {
        int d = db * 128 + wc0 + fj * 16 + lo;
        Out[orow + d] = acc[fi][fj][r4] + p;
      }
    }
}

}  // namespace

extern "C" void kernel_launch(void* const* d_in, const int* in_sizes, int n_in,
                              void* d_out, int out_size, void* d_ws,
                              size_t ws_size, hipStream_t stream) {
  const float* input = (const float*)d_in[0];
  const float* eqk = (const float*)d_in[1];
  const float* Wq = (const float*)d_in[2];
  const float* bq = (const float*)d_in[3];
  const float* Wk = (const float*)d_in[4];
  const float* bk = (const float*)d_in[5];
  const float* Wp = (const float*)d_in[6];
  const float* bp = (const float*)d_in[7];
  float* out = (float*)d_out;

  ushort* ws = (ushort*)d_ws;
  ushort* WqT = ws;                  // 65536
  ushort* WkT = WqT + 65536;         // 65536
  ushort* xg = WkT + 65536;          // 8388608  grouped v  [bm][w8][c][8]
  ushort* kg = xg + 8388608;         // 8388608  grouped phi_k
  ushort* qf = kg + 8388608;         // 524288   phi_q flat [2048][256]
  ushort* kvt = qf + 524288;         // 2097152  KVT [bm][d][c]

  wt_kernel<<<dim3(4, 4, 2), 256, 0, stream>>>(Wq, Wk, WqT, WkT);
  regroup_kernel<<<dim3(16, 64, 2), 256, 0, stream>>>(input, xg);
  proj_kernel<<<dim3(1088), 256, 0, stream>>>(input, WqT, WkT, bq, bk, kg, qf);
  kv_kernel<<<dim3(512), 256, 0, stream>>>(kg, xg, kvt);
  out_kernel<<<dim3(512), 256, 0, stream>>>(qf, kvt, eqk, Wp, bp, out);
}

// Round 15
// 133.522 us; speedup vs baseline: 1.2957x; 1.1531x over previous
//
#include <hip/hip_runtime.h>

typedef __attribute__((ext_vector_type(8))) short s16x8;
typedef __attribute__((ext_vector_type(8))) ushort u16x8;
typedef __attribute__((ext_vector_type(4))) ushort u16x4;
typedef __attribute__((ext_vector_type(4))) float f32x4v;

namespace {

constexpr int kB = 2;
constexpr int kN = 16384;
constexpr int kC = 256;
constexpr int kQR = 1024;

__device__ __forceinline__ ushort f2bf(float f) {
  union { float f; uint u; } v; v.f = f;
  uint u = v.u + 0x7fffu + ((v.u >> 16) & 1u);
  return (ushort)(u >> 16);
}

__device__ __forceinline__ float phi_act(float x) {
  return x > 0.f ? x + 2.f : __expf(x) + 1.f;
}

__device__ __forceinline__ void gl16(const ushort* g, ushort* l) {
  __builtin_amdgcn_global_load_lds(
      (const __attribute__((address_space(1))) void*)g,
      (__attribute__((address_space(3))) void*)l, 16, 0, 0);
}

// ---- 1. weight transpose+convert: W[k][j] f32 -> WT[j][k] bf16
__global__ __launch_bounds__(256) void wt_kernel(const float* __restrict__ Wq,
                                                 const float* __restrict__ Wk,
                                                 ushort* __restrict__ WqT,
                                                 ushort* __restrict__ WkT) {
  __shared__ float ts[64][65];
  const float* W = blockIdx.z ? Wk : Wq;
  ushort* WT = blockIdx.z ? WkT : WqT;
  const int bi = blockIdx.x, bj = blockIdx.y, t = threadIdx.x;
  for (int rep = 0; rep < 16; ++rep) {
    int e = rep * 256 + t, r = e >> 6, c = e & 63;
    ts[r][c] = W[(size_t)(bi * 64 + r) * kC + bj * 64 + c];
  }
  __syncthreads();
  for (int rep = 0; rep < 16; ++rep) {
    int e = rep * 256 + t, j = e >> 6, k = e & 63;
    WT[(size_t)(bj * 64 + j) * kC + bi * 64 + k] = f2bf(ts[k][j]);
  }
}

// ---- 2. fused projections + v-regroup (R7 record holder).
// blocks 0..255: K-mode: rows 128/block; phi_k -> kg grouped; X -> xg grouped.
// blocks 256..271: Q-mode: phi_q -> qf flat.
__global__ __launch_bounds__(512) void proj_fused(
    const float* __restrict__ X, const ushort* __restrict__ WqT,
    const ushort* __restrict__ WkT, const float* __restrict__ bq,
    const float* __restrict__ bk, ushort* __restrict__ xg,
    ushort* __restrict__ kg, ushort* __restrict__ qf) {
  __shared__ __align__(16) ushort smem[24576];  // 48 KB

  const int t = threadIdx.x, lane = t & 63, wv = t >> 6;
  const int bx = blockIdx.x;
  const bool kmode = bx < 256;
  int b, n0;
  const ushort* WT;
  const float* bias;
  if (kmode) {
    b = bx >> 7; n0 = (bx & 127) * 128; WT = WkT; bias = bk;
  } else {
    int i = bx - 256; b = i >> 3; n0 = (i & 7) * 128; WT = WqT; bias = bq;
  }
  const int wgrp = bx & 127;
  const float* Xbase = X + ((size_t)b * kN + n0) * kC;

  const int m = t >> 5, cl = t & 31;    // A-stage: (m, c) x 8 w-rows
  const int bj = t >> 2, bch = t & 3;   // B-stage

  float fa[8];
  u16x8 rb0, rb1;
  auto stageLoad = [&](int ks) {
    const int k0 = ks * 32;
#pragma unroll
    for (int wl = 0; wl < 8; ++wl)
      fa[wl] = Xbase[(size_t)(wl * 16 + m) * kC + k0 + cl];
    rb0 = *reinterpret_cast<const u16x8*>(WT + (size_t)bj * kC + k0 + bch * 8);
    rb1 = *reinterpret_cast<const u16x8*>(WT + (size_t)(bj + 128) * kC + k0 + bch * 8);
  };
  auto stageWrite = [&](int h, int ks) {
    ushort* A = smem + h * 4096;
    ushort* B = smem + 8192 + h * 8192;
    u16x8 vx;
#pragma unroll
    for (int wl = 0; wl < 8; ++wl) {
      int row = wl * 16 + m;
      ushort bf = f2bf(fa[wl]);
      A[row * 32 + (((cl >> 3) ^ ((row >> 1) & 3)) << 3) + (cl & 7)] = bf;
      vx[wl] = bf;
    }
    *reinterpret_cast<u16x8*>(B + bj * 32 + ((bch ^ ((bj >> 1) & 3)) << 3)) = rb0;
    *reinterpret_cast<u16x8*>(B + (bj + 128) * 32 + ((bch ^ (((bj + 128) >> 1) & 3)) << 3)) = rb1;
    if (kmode) {
      *reinterpret_cast<u16x8*>(
          xg + (((size_t)(b * 16 + m) * 128 + wgrp) * 256 + ks * 32 + cl) * 8) = vx;
    }
  };

  f32x4v acc[4][4] = {};
  const int lo = lane & 15, hi = lane >> 4;
  const int wr0 = (wv >> 2) * 64, wc0 = (wv & 3) * 64;
  auto mma = [&](int h) {
    const ushort* A = smem + h * 4096;
    const ushort* B = smem + 8192 + h * 8192;
    s16x8 af[4], bf[4];
#pragma unroll
    for (int i = 0; i < 4; ++i) {
      int r = wr0 + i * 16 + lo;
      af[i] = *reinterpret_cast<const s16x8*>(A + r * 32 + ((hi ^ ((r >> 1) & 3)) << 3));
    }
#pragma unroll
    for (int j = 0; j < 4; ++j) {
      int cj = wc0 + j * 16 + lo;
      bf[j] = *reinterpret_cast<const s16x8*>(B + cj * 32 + ((hi ^ ((cj >> 1) & 3)) << 3));
    }
#pragma unroll
    for (int i = 0; i < 4; ++i)
#pragma unroll
      for (int j = 0; j < 4; ++j)
        acc[i][j] = __builtin_amdgcn_mfma_f32_16x16x32_bf16(af[i], bf[j], acc[i][j], 0, 0, 0);
  };

  stageLoad(0);
  stageWrite(0, 0);
  __syncthreads();
  int cur = 0;
  for (int ks = 0; ks < 8; ++ks) {
    if (ks < 7) stageLoad(ks + 1);
    __builtin_amdgcn_sched_barrier(0);
    mma(cur);
    __builtin_amdgcn_sched_barrier(0);
    if (ks < 7) stageWrite(cur ^ 1, ks + 1);
    __syncthreads();
    cur ^= 1;
  }

  float bv[4];
#pragma unroll
  for (int fj = 0; fj < 4; ++fj) bv[fj] = bias[wc0 + fj * 16 + lo];

  if (kmode) {
    u16x8 vout[8];
    ushort* ep = smem;  // [64][260]
#pragma unroll
    for (int h = 0; h < 2; ++h) {
      __syncthreads();
      if ((wv >> 2) == h) {
#pragma unroll
        for (int fi = 0; fi < 4; ++fi)
#pragma unroll
          for (int fj = 0; fj < 4; ++fj)
#pragma unroll
            for (int r4 = 0; r4 < 4; ++r4) {
              int rl = fi * 16 + hi * 4 + r4;
              int col = wc0 + fj * 16 + lo;
              ep[rl * 260 + col] = f2bf(phi_act(acc[fi][fj][r4] + bv[fj]));
            }
      }
      __syncthreads();
#pragma unroll
      for (int j = 0; j < 8; ++j) {
        int c = j * 32 + cl;
#pragma unroll
        for (int wl = 0; wl < 4; ++wl)
          vout[j][h * 4 + wl] = ep[(wl * 16 + m) * 260 + c];
      }
    }
#pragma unroll
    for (int j = 0; j < 8; ++j) {
      int c = j * 32 + cl;
      *reinterpret_cast<u16x8*>(
          kg + (((size_t)(b * 16 + m) * 128 + wgrp) * 256 + c) * 8) = vout[j];
    }
  } else {
#pragma unroll
    for (int fi = 0; fi < 4; ++fi)
#pragma unroll
      for (int fj = 0; fj < 4; ++fj)
#pragma unroll
        for (int r4 = 0; r4 < 4; ++r4) {
          int row = n0 + wr0 + fi * 16 + hi * 4 + r4;
          int col = wc0 + fj * 16 + lo;
          qf[((size_t)b * kQR + row) * kC + col] = f2bf(phi_act(acc[fi][fj][r4] + bv[fj]));
        }
  }
}

// ---- 3. KV GEMM per (b,m) via global_load_lds, chunk-major LDS (R14 form).
__global__ __launch_bounds__(256) void kv_kernel(const ushort* __restrict__ kg,
                                                 const ushort* __restrict__ xg,
                                                 ushort* __restrict__ kvt) {
  __shared__ __align__(16) ushort smem[32768];  // 64KB
  const int t = threadIdx.x, lane = t & 63, wv = t >> 6;
  const int swz = (blockIdx.x & 7) * 64 + (blockIdx.x >> 3);
  const int bm = swz >> 4, cb = swz & 3, db = (swz >> 2) & 3;
  const int c_l = t & 63;
  const ushort* Abase = kg + (size_t)bm * 262144 + (size_t)(cb * 64) * 8;
  const ushort* Bbase = xg + (size_t)bm * 262144 + (size_t)(db * 64) * 8;

  auto STAGE = [&](int h, int s) {
    ushort* A = smem + h * 8192;
    ushort* B = smem + 16384 + h * 8192;
#pragma unroll
    for (int i = 0; i < 4; ++i) {
      int o = i * 4 + wv;
      size_t goff = ((size_t)(s * 16 + o) * 256 + c_l) * 8;
      int loff = (i * 256 + t) * 8;
      gl16(Abase + goff, A + loff);
      gl16(Bbase + goff, B + loff);
    }
  };

  const int lo = lane & 15, hi = lane >> 4;
  const int wr0 = (wv >> 1) * 32, wc0 = (wv & 1) * 32;
  f32x4v acc[2][2] = {};
  auto MMA = [&](int h) {
    const ushort* A = smem + h * 8192;
    const ushort* B = smem + 16384 + h * 8192;
#pragma unroll
    for (int kk = 0; kk < 4; ++kk) {
      const int o = kk * 4 + hi;
      s16x8 a0 = *reinterpret_cast<const s16x8*>(A + o * 512 + (wr0 + lo) * 8);
      s16x8 a1 = *reinterpret_cast<const s16x8*>(A + o * 512 + (wr0 + 16 + lo) * 8);
      s16x8 b0 = *reinterpret_cast<const s16x8*>(B + o * 512 + (wc0 + lo) * 8);
      s16x8 b1 = *reinterpret_cast<const s16x8*>(B + o * 512 + (wc0 + 16 + lo) * 8);
      acc[0][0] = __builtin_amdgcn_mfma_f32_16x16x32_bf16(a0, b0, acc[0][0], 0, 0, 0);
      acc[0][1] = __builtin_amdgcn_mfma_f32_16x16x32_bf16(a0, b1, acc[0][1], 0, 0, 0);
      acc[1][0] = __builtin_amdgcn_mfma_f32_16x16x32_bf16(a1, b0, acc[1][0], 0, 0, 0);
      acc[1][1] = __builtin_amdgcn_mfma_f32_16x16x32_bf16(a1, b1, acc[1][1], 0, 0, 0);
    }
  };

  STAGE(0, 0);
  __syncthreads();
  int cur = 0;
  for (int s = 0; s < 8; ++s) {
    if (s < 7) STAGE(cur ^ 1, s + 1);
    __builtin_amdgcn_sched_barrier(0);
    MMA(cur);
    __syncthreads();
    cur ^= 1;
  }
#pragma unroll
  for (int fi = 0; fi < 2; ++fi)
#pragma unroll
    for (int fj = 0; fj < 2; ++fj) {
      int d = db * 64 + wc0 + fj * 16 + lo;
      int c = cb * 64 + wr0 + fi * 16 + hi * 4;
      u16x4 v = {f2bf(acc[fi][fj][0]), f2bf(acc[fi][fj][1]),
                 f2bf(acc[fi][fj][2]), f2bf(acc[fi][fj][3])};
      *reinterpret_cast<u16x4*>(kvt + ((size_t)bm * 256 + d) * 256 + c) = v;
    }
}

// ---- 4. out GEMM per (b,m) (R13 form: 32KB dbuf, 2 blocks/CU, XCD swizzle).
__global__ __launch_bounds__(256) void out_kernel(
    const ushort* __restrict__ qf, const ushort* __restrict__ kvt,
    const float* __restrict__ EQK, const float* __restrict__ Wp,
    const float* __restrict__ bp, float* __restrict__ Out) {
  __shared__ __align__(16) ushort smem[16384];
  __shared__ float Ps[128];
  const int t = threadIdx.x, lane = t & 63, wv = t >> 6;
  const int swz = (blockIdx.x & 7) * 64 + (blockIdx.x >> 3);
  const int bm = swz >> 4, qb = swz & 7, db = (swz >> 3) & 1;
  const int b = bm >> 4, mm = bm & 15;
  if (t < 128) {
    int qr = qb * 128 + t;
    const float* e = EQK + (((size_t)(b * 1024 + (qr >> 4)) * 16 + (qr & 15)) * 16 + mm) * 3;
    Ps[t] = e[0] * Wp[0] + e[1] * Wp[1] + e[2] * Wp[2] + bp[0];
  }
  const int r2 = t >> 2, ch = t & 3;

  u16x8 ra0, ra1, rb0, rb1;
  auto stageLoad = [&](int ks) {
    int k0 = ks * 32;
    const ushort* Aq = qf + ((size_t)b * kQR + qb * 128) * kC;
    const ushort* Bk = kvt + ((size_t)bm * 256 + db * 128) * kC;
    ra0 = *reinterpret_cast<const u16x8*>(Aq + (size_t)r2 * kC + k0 + ch * 8);
    ra1 = *reinterpret_cast<const u16x8*>(Aq + (size_t)(r2 + 64) * kC + k0 + ch * 8);
    rb0 = *reinterpret_cast<const u16x8*>(Bk + (size_t)r2 * kC + k0 + ch * 8);
    rb1 = *reinterpret_cast<const u16x8*>(Bk + (size_t)(r2 + 64) * kC + k0 + ch * 8);
  };
  auto stageWrite = [&](int h) {
    ushort* A = smem + h * 4096;
    ushort* B = smem + 8192 + h * 4096;
    *reinterpret_cast<u16x8*>(A + r2 * 32 + ((ch ^ ((r2 >> 1) & 3)) << 3)) = ra0;
    *reinterpret_cast<u16x8*>(A + (r2 + 64) * 32 + ((ch ^ (((r2 + 64) >> 1) & 3)) << 3)) = ra1;
    *reinterpret_cast<u16x8*>(B + r2 * 32 + ((ch ^ ((r2 >> 1) & 3)) << 3)) = rb0;
    *reinterpret_cast<u16x8*>(B + (r2 + 64) * 32 + ((ch ^ (((r2 + 64) >> 1) & 3)) << 3)) = rb1;
  };

  f32x4v acc[4][4] = {};
  const int lo = lane & 15, hi = lane >> 4;
  const int wr0 = (wv >> 1) * 64, wc0 = (wv & 1) * 64;
  auto mma = [&](int h) {
    const ushort* A = smem + h * 4096;
    const ushort* B = smem + 8192 + h * 4096;
    s16x8 af[4], bf[4];
#pragma unroll
    for (int i = 0; i < 4; ++i) {
      int r = wr0 + i * 16 + lo;
      af[i] = *reinterpret_cast<const s16x8*>(A + r * 32 + ((hi ^ ((r >> 1) & 3)) << 3));
    }
#pragma unroll
    for (int j = 0; j < 4; ++j) {
      int c = wc0 + j * 16 + lo;
      bf[j] = *reinterpret_cast<const s16x8*>(B + c * 32 + ((hi ^ ((c >> 1) & 3)) << 3));
    }
#pragma unroll
    for (int i = 0; i < 4; ++i)
#pragma unroll
      for (int j = 0; j < 4; ++j)
        acc[i][j] = __builtin_amdgcn_mfma_f32_16x16x32_bf16(af[i], bf[j], acc[i][j], 0, 0, 0);
  };

  stageLoad(0);
  stageWrite(0);
  __syncthreads();
  int cur = 0;
  for (int ks = 0; ks < 8; ++ks) {
    if (ks < 7) stageLoad(ks + 1);
    __builtin_amdgcn_sched_barrier(0);
    mma(cur);
    __builtin_amdgcn_sched_barrier(0);
    if (ks < 7) stageWrite(cur ^ 1);
    __syncthreads();
    cur ^= 1;
  }
#pragma unroll
  for (int fi = 0; fi < 4; ++fi)
#pragma unroll
    for (int r4 = 0; r4 < 4; ++r4) {
      int rowl = wr0 + fi * 16 + hi * 4 + r4;
      int qr = qb * 128 + rowl;
      float p = Ps[rowl];
      size_t orow = ((size_t)b * kN + (size_t)qr * 16 + mm) * kC;
#pragma unroll
      for (int fj = 0; fj < 4; ++fj) {
        int d = db * 128 + wc0 + fj * 16 + lo;
        Out[orow + d] = acc[fi][fj][r4] + p;
      }
    }
}

}  // namespace

extern "C" void kernel_launch(void* const* d_in, const int* in_sizes, int n_in,
                              void* d_out, int out_size, void* d_ws,
                              size_t ws_size, hipStream_t stream) {
  const float* input = (const float*)d_in[0];
  const float* eqk = (const float*)d_in[1];
  const float* Wq = (const float*)d_in[2];
  const float* bq = (const float*)d_in[3];
  const float* Wk = (const float*)d_in[4];
  const float* bk = (const float*)d_in[5];
  const float* Wp = (const float*)d_in[6];
  const float* bp = (const float*)d_in[7];
  float* out = (float*)d_out;

  ushort* ws = (ushort*)d_ws;
  ushort* WqT = ws;                  // 65536
  ushort* WkT = WqT + 65536;         // 65536
  ushort* xg = WkT + 65536;          // 8388608  grouped v  [bm][w8][c][8]
  ushort* kg = xg + 8388608;         // 8388608  grouped phi_k
  ushort* qf = kg + 8388608;         // 524288   phi_q flat [2048][256]
  ushort* kvt = qf + 524288;         // 2097152  KVT [bm][d][c]

  wt_kernel<<<dim3(4, 4, 2), 256, 0, stream>>>(Wq, Wk, WqT, WkT);
  proj_fused<<<dim3(272), 512, 0, stream>>>(input, WqT, WkT, bq, bk, xg, kg, qf);
  kv_kernel<<<dim3(512), 256, 0, stream>>>(kg, xg, kvt);
  out_kernel<<<dim3(512), 256, 0, stream>>>(qf, kvt, eqk, Wp, bp, out);
}